// Round 2
// baseline (9478.127 us; speedup 1.0000x reference)
//
#include <hip/hip_runtime.h>

#define VSZ 512
#define LSEQ 128
#define BT 16
#define NW 8
#define NTHR 512
#define PFD 8   // prefetch distance in k-iters; 64 % PFD == 0 keeps slots consistent

using short8  = __attribute__((ext_vector_type(8))) short;
using short4v = __attribute__((ext_vector_type(4))) short;
using floatx4 = __attribute__((ext_vector_type(4))) float;

static __device__ __forceinline__ short f2bf(float f) {
    union { float f; unsigned u; } v; v.f = f;
    unsigned u = v.u;
    unsigned r = (u + 0x7fffu + ((u >> 16) & 1u)) >> 16;
    return (short)r;
}
static __device__ __forceinline__ float bf2f(short s) {
    union { unsigned u; float f; } v; v.u = ((unsigned)(unsigned short)s) << 16;
    return v.f;
}
static __device__ __forceinline__ float fast_rcp(float x) { return __builtin_amdgcn_rcpf(x); }
static __device__ __forceinline__ float sigm(float x)   { return fast_rcp(1.0f + __expf(-x)); }
static __device__ __forceinline__ float tanh_f(float x) { return 1.0f - 2.0f * fast_rcp(__expf(2.0f * x) + 1.0f); }

// ---- prep: W_hh (f32, [2048][512]) -> bf16, B-fragment order, LINEAR per-wave stream.
// Tile T = vt*64 + k*4 + g  (vt: v-tile 0..31, k: K-chunk 0..15, g: gate 0..3)
// lane l of tile T holds W_hh[g*512 + vt*16 + (l&15)][k*32 + (l>>4)*8 + 0..7]
__global__ void prep_wb(const float* __restrict__ Whh, short* __restrict__ Wb) {
    int tid = threadIdx.x;
    int lane = tid & 63;
    int wv = tid >> 6;
    int T = blockIdx.x * 8 + wv;              // 0..2047
    int g  = T & 3;
    int k  = (T >> 2) & 15;
    int vt = T >> 6;
    int l15 = lane & 15, lg = lane >> 4;
    int j = g * 512 + vt * 16 + l15;
    int col = k * 32 + lg * 8;
    const float* src = Whh + (size_t)j * 512 + col;
    short8 o;
#pragma unroll
    for (int i = 0; i < 8; ++i) o[i] = f2bf(src[i]);
    *(short8*)(Wb + (size_t)T * 512 + lane * 8) = o;
}

// ---- prep: W_xb[a][v][g] = bf16( W_ih[g*512+v][a] + b_ih[j] + b_hh[j] )
__global__ void prep_wxb(const float* __restrict__ Wih, const float* __restrict__ bih,
                         const float* __restrict__ bhh, short* __restrict__ Wxb) {
    __shared__ float tile[64][65];
    int j0 = blockIdx.x * 64;     // j tile (32 of them)
    int a0 = blockIdx.y * 64;     // a tile (8 of them)
    int tid = threadIdx.x;
    for (int i = tid; i < 4096; i += NTHR) {
        int r = i >> 6, c = i & 63;
        int j = j0 + r;
        tile[r][c] = Wih[(size_t)j * 512 + a0 + c] + bih[j] + bhh[j];
    }
    __syncthreads();
    int g = j0 >> 9;
    int v0 = j0 & 511;
    for (int i = tid; i < 4096; i += NTHR) {
        int r = i >> 6, c = i & 63;   // r: a-offset, c: j-offset
        Wxb[(((size_t)(a0 + r)) * 512 + v0 + c) * 4 + g] = f2bf(tile[c][r]);
    }
}

// ---- main persistent decoder: 32 blocks x 16 rows, 8 waves each
__launch_bounds__(NTHR, 2)
__global__ void decoder_main(const float* __restrict__ x, const short* __restrict__ Wb,
                             const short* __restrict__ Wxb, float* __restrict__ out) {
    __shared__ short hbf[2][BT][520];     // h as bf16, padded rows
    __shared__ float wsum[NW][BT];
    __shared__ float wmaxv[NW][BT];
    __shared__ int   wmaxi[NW][BT];
    __shared__ float rinv[BT];
    __shared__ int   ridx[BT];

    const int tid = threadIdx.x;
    const int lane = tid & 63;
    const int w = tid >> 6;         // wave 0..7 -> owns v in [64w, 64w+64)
    const int l15 = lane & 15;
    const int lg  = lane >> 4;      // 0..3
    const int row0 = blockIdx.x * BT;

    // h0 = x (bf16 into LDS); out[:,127,:] = PAD one-hot; idx = SOS
    for (int i = tid; i < BT * VSZ; i += NTHR) {
        int r = i >> 9, k = i & 511;
        hbf[0][r][k] = f2bf(x[(size_t)(row0 + r) * VSZ + k]);
    }
    for (int i = tid; i < BT * VSZ; i += NTHR) {
        int r = i >> 9, v = i & 511;
        out[((size_t)(row0 + r) * LSEQ + (LSEQ - 1)) * VSZ + v] = (v == 0) ? 1.0f : 0.0f;
    }
    if (tid < BT) ridx[tid] = 1;    // SOS_ID

    float c[4][4];
#pragma unroll
    for (int qd = 0; qd < 4; ++qd)
#pragma unroll
        for (int q = 0; q < 4; ++q) c[qd][q] = 0.0f;

    // per-wave linear W stream: iter qi (0..63) at byte qi*4096, gates at +0/+1024/+2048/+3072
    const short* wb_lane = Wb + (size_t)w * 131072 + (size_t)lane * 8;

    // modulo-scheduled B-fragment pipeline, depth PFD (loads land directly in
    // their consumption slot; no register copies -> no same-iter waitcnt)
    short8 bb[PFD][4];
#pragma unroll
    for (int qi = 0; qi < PFD; ++qi)
#pragma unroll
        for (int g = 0; g < 4; ++g)
            bb[qi][g] = *(const short8*)(wb_lane + qi * 2048 + g * 512);

    __syncthreads();

    int buf = 0;
    for (int t = 0; t < LSEQ - 1; ++t) {
        float ex[4][4];
#pragma unroll
        for (int qd = 0; qd < 4; ++qd) {
            // one-hot x-side gather for this quad (consumed after the k-loop)
            short4v wx[4];
#pragma unroll
            for (int q = 0; q < 4; ++q) {
                int aid = ridx[4 * lg + q];
                int v = w * 64 + qd * 16 + l15;
                wx[q] = *(const short4v*)(Wxb + ((size_t)aid * 512 + v) * 4);
            }

            floatx4 ai = {0,0,0,0}, af = {0,0,0,0}, ag = {0,0,0,0}, ao = {0,0,0,0};
#pragma unroll
            for (int k = 0; k < 16; ++k) {
                int qi = qd * 16 + k;
                int s = qi & (PFD - 1);
                short8 av = *(const short8*)&hbf[buf][l15][k * 32 + lg * 8];
                ai = __builtin_amdgcn_mfma_f32_16x16x32_bf16(av, bb[s][0], ai, 0, 0, 0);
                af = __builtin_amdgcn_mfma_f32_16x16x32_bf16(av, bb[s][1], af, 0, 0, 0);
                ag = __builtin_amdgcn_mfma_f32_16x16x32_bf16(av, bb[s][2], ag, 0, 0, 0);
                ao = __builtin_amdgcn_mfma_f32_16x16x32_bf16(av, bb[s][3], ao, 0, 0, 0);
                // refill this slot for iteration qi+PFD (wraps into next step: W is
                // step-invariant, so the wrapped load is always the right data)
                int qn = (qi + PFD) & 63;
#pragma unroll
                for (int g = 0; g < 4; ++g)
                    bb[s][g] = *(const short8*)(wb_lane + qn * 2048 + g * 512);
            }

            // pointwise LSTM for this quad; c stays in registers
#pragma unroll
            for (int q = 0; q < 4; ++q) {
                float gi = ai[q] + bf2f(wx[q][0]);
                float gf = af[q] + bf2f(wx[q][1]);
                float gg = ag[q] + bf2f(wx[q][2]);
                float go = ao[q] + bf2f(wx[q][3]);
                float cn = sigm(gf) * c[qd][q] + sigm(gi) * tanh_f(gg);
                c[qd][q] = cn;
                float hn = sigm(go) * tanh_f(cn);
                hbf[buf ^ 1][4 * lg + q][w * 64 + qd * 16 + l15] = f2bf(hn);
                ex[qd][q] = __expf(hn);   // h in (-1,1): no max-subtraction needed
            }
        }

        // per-row softmax-denominator + argmax partials (wave-level)
#pragma unroll
        for (int q = 0; q < 4; ++q) {
            float s = ex[0][q] + ex[1][q] + ex[2][q] + ex[3][q];
            float mv = ex[0][q]; int mi = w * 64 + l15;
#pragma unroll
            for (int qd = 1; qd < 4; ++qd) {
                int v = w * 64 + qd * 16 + l15;
                if (ex[qd][q] > mv) { mv = ex[qd][q]; mi = v; }
            }
#pragma unroll
            for (int m = 1; m < 16; m <<= 1) {
                s += __shfl_xor(s, m);
                float mv2 = __shfl_xor(mv, m);
                int   mi2 = __shfl_xor(mi, m);
                if (mv2 > mv || (mv2 == mv && mi2 < mi)) { mv = mv2; mi = mi2; }
            }
            if (l15 == 0) { int r = 4 * lg + q; wsum[w][r] = s; wmaxv[w][r] = mv; wmaxi[w][r] = mi; }
        }
        __syncthreads();
        if (tid < BT) {
            float s = 0.f;
#pragma unroll
            for (int ww = 0; ww < NW; ++ww) s += wsum[ww][tid];
            rinv[tid] = 1.0f / s;
            float mv = wmaxv[0][tid]; int mi = wmaxi[0][tid];
#pragma unroll
            for (int ww = 1; ww < NW; ++ww) {
                float mv2 = wmaxv[ww][tid]; int mi2 = wmaxi[ww][tid];
                if (mv2 > mv || (mv2 == mv && mi2 < mi)) { mv = mv2; mi = mi2; }
            }
            ridx[tid] = mi;
        }
        __syncthreads();

        // write probas for step t
#pragma unroll
        for (int qd = 0; qd < 4; ++qd)
#pragma unroll
            for (int q = 0; q < 4; ++q) {
                int r = 4 * lg + q;
                out[((size_t)(row0 + r) * LSEQ + t) * VSZ + w * 64 + qd * 16 + l15] = ex[qd][q] * rinv[r];
            }
        buf ^= 1;
    }
}

extern "C" void kernel_launch(void* const* d_in, const int* in_sizes, int n_in,
                              void* d_out, int out_size, void* d_ws, size_t ws_size,
                              hipStream_t stream) {
    const float* x    = (const float*)d_in[0];
    const float* W_ih = (const float*)d_in[1];
    const float* W_hh = (const float*)d_in[2];
    const float* b_ih = (const float*)d_in[3];
    const float* b_hh = (const float*)d_in[4];

    short* Wb  = (short*)d_ws;                 // 2048*512 bf16 = 2 MB (swizzled W_hh)
    short* Wxb = Wb + (size_t)2048 * 512;      // 512*512*4 bf16 = 2 MB (one-hot gather table)

    prep_wb<<<256, NTHR, 0, stream>>>(W_hh, Wb);
    prep_wxb<<<dim3(32, 8), NTHR, 0, stream>>>(W_ih, b_ih, b_hh, Wxb);
    decoder_main<<<32, NTHR, 0, stream>>>(x, Wb, Wxb, (float*)d_out);
}

// Round 3
// 3221.474 us; speedup vs baseline: 2.9422x; 2.9422x over previous
//
#include <hip/hip_runtime.h>

#define VSZ 512
#define LSEQ 128
#define BT 16
#define NW 8
#define NTHR 512
#define PFD 8   // prefetch depth (k-iters); 64 % PFD == 0

using short8  = __attribute__((ext_vector_type(8))) short;
using short4v = __attribute__((ext_vector_type(4))) short;
using floatx4 = __attribute__((ext_vector_type(4))) float;

static __device__ __forceinline__ short f2bf(float f) {
    union { float f; unsigned u; } v; v.f = f;
    unsigned u = v.u;
    unsigned r = (u + 0x7fffu + ((u >> 16) & 1u)) >> 16;
    return (short)r;
}
static __device__ __forceinline__ float bf2f(short s) {
    union { unsigned u; float f; } v; v.u = ((unsigned)(unsigned short)s) << 16;
    return v.f;
}
static __device__ __forceinline__ float fast_rcp(float x) { return __builtin_amdgcn_rcpf(x); }
static __device__ __forceinline__ float sigm(float x)   { return fast_rcp(1.0f + __expf(-x)); }
static __device__ __forceinline__ float tanh_f(float x) { return 1.0f - 2.0f * fast_rcp(__expf(2.0f * x) + 1.0f); }

// block-wide barrier that waits LDS ops only — does NOT drain vmcnt, so the
// W-load pipeline stays in flight across steps (unlike __syncthreads()).
static __device__ __forceinline__ void block_sync_lgkm() {
    __builtin_amdgcn_sched_barrier(0);
    asm volatile("s_waitcnt lgkmcnt(0)" ::: "memory");
    __builtin_amdgcn_s_barrier();
    __builtin_amdgcn_sched_barrier(0);
}

// ---- prep: W_hh (f32, [2048][512]) -> bf16, B-fragment order, LINEAR per-wave stream.
// Tile T = vt*64 + k*4 + g; lane l holds W_hh[g*512+vt*16+(l&15)][k*32+(l>>4)*8+0..7]
__global__ void prep_wb(const float* __restrict__ Whh, short* __restrict__ Wb) {
    int tid = threadIdx.x;
    int lane = tid & 63;
    int wv = tid >> 6;
    int T = blockIdx.x * 8 + wv;              // 0..2047
    int g  = T & 3;
    int k  = (T >> 2) & 15;
    int vt = T >> 6;
    int l15 = lane & 15, lg = lane >> 4;
    int j = g * 512 + vt * 16 + l15;
    int col = k * 32 + lg * 8;
    const float* src = Whh + (size_t)j * 512 + col;
    short8 o;
#pragma unroll
    for (int i = 0; i < 8; ++i) o[i] = f2bf(src[i]);
    *(short8*)(Wb + (size_t)T * 512 + lane * 8) = o;
}

// ---- prep: W_xb[a][v][g] = bf16( W_ih[g*512+v][a] + b_ih[j] + b_hh[j] )
__global__ void prep_wxb(const float* __restrict__ Wih, const float* __restrict__ bih,
                         const float* __restrict__ bhh, short* __restrict__ Wxb) {
    __shared__ float tile[64][65];
    int j0 = blockIdx.x * 64;
    int a0 = blockIdx.y * 64;
    int tid = threadIdx.x;
    for (int i = tid; i < 4096; i += NTHR) {
        int r = i >> 6, c = i & 63;
        int j = j0 + r;
        tile[r][c] = Wih[(size_t)j * 512 + a0 + c] + bih[j] + bhh[j];
    }
    __syncthreads();
    int v0 = j0 & 511;
    for (int i = tid; i < 4096; i += NTHR) {
        int r = i >> 6, c = i & 63;
        Wxb[(((size_t)(a0 + r)) * 512 + v0 + c) * 4 + (j0 >> 9)] = f2bf(tile[c][r]);
    }
}

// ---- main persistent decoder: 32 blocks x 16 rows, 8 waves each
__launch_bounds__(NTHR, 2)
__global__ void decoder_main(const float* __restrict__ x, const short* __restrict__ Wb,
                             const short* __restrict__ Wxb, float* __restrict__ out) {
    __shared__ short hbf[2][BT][520];
    __shared__ float wsum[NW][BT];
    __shared__ float wmaxv[NW][BT];
    __shared__ int   wmaxi[NW][BT];
    __shared__ float rinv[BT];
    __shared__ int   ridx[BT];

    const int tid = threadIdx.x;
    const int lane = tid & 63;
    const int w = tid >> 6;
    const int l15 = lane & 15;
    const int lg  = lane >> 4;
    const int row0 = blockIdx.x * BT;

    for (int i = tid; i < BT * VSZ; i += NTHR) {
        int r = i >> 9, k = i & 511;
        hbf[0][r][k] = f2bf(x[(size_t)(row0 + r) * VSZ + k]);
    }
    for (int i = tid; i < BT * VSZ; i += NTHR) {
        int r = i >> 9, v = i & 511;
        __builtin_nontemporal_store((v == 0) ? 1.0f : 0.0f,
            &out[((size_t)(row0 + r) * LSEQ + (LSEQ - 1)) * VSZ + v]);
    }
    if (tid < BT) ridx[tid] = 1;    // SOS_ID

    float c[4][4];
#pragma unroll
    for (int qd = 0; qd < 4; ++qd)
#pragma unroll
        for (int q = 0; q < 4; ++q) c[qd][q] = 0.0f;

    // per-wave linear W stream: iter qi -> byte qi*4096, gates at +0/1024/2048/3072
    const short* wb_lane = Wb + (size_t)w * 131072 + (size_t)lane * 8;

    __syncthreads();   // before pipeline start (this one may drain vmcnt: fine)

    // ---- fill the 8-deep B-fragment pipeline with asm loads (compiler cannot sink these)
    short8 bb[PFD][4];
#pragma unroll
    for (int qi = 0; qi < PFD; ++qi) {
        const short* p = wb_lane + qi * 2048;
        asm volatile("global_load_dwordx4 %0, %1, off"             : "=v"(bb[qi][0]) : "v"(p));
        asm volatile("global_load_dwordx4 %0, %1, off offset:1024" : "=v"(bb[qi][1]) : "v"(p));
        asm volatile("global_load_dwordx4 %0, %1, off offset:2048" : "=v"(bb[qi][2]) : "v"(p));
        asm volatile("global_load_dwordx4 %0, %1, off offset:3072" : "=v"(bb[qi][3]) : "v"(p));
    }

    int buf = 0;
    for (int t = 0; t < LSEQ - 1; ++t) {
        float ex[4][4];
#pragma unroll
        for (int qd = 0; qd < 4; ++qd) {
            // one-hot x-side gathers (asm too: keep ALL in-loop vmem manually counted)
            short4v wx[4];
#pragma unroll
            for (int q = 0; q < 4; ++q) {
                int aid = ridx[4 * lg + q];
                const short* gp = Wxb + ((size_t)aid * 512 + (w * 64 + qd * 16 + l15)) * 4;
                asm volatile("global_load_dwordx2 %0, %1, off" : "=v"(wx[q]) : "v"(gp));
            }

            floatx4 ai = {0,0,0,0}, af = {0,0,0,0}, ag = {0,0,0,0}, ao = {0,0,0,0};
#pragma unroll
            for (int k = 0; k < 16; ++k) {
                const int qi = qd * 16 + k;
                const int s = qi & (PFD - 1);
                short8 av = *(const short8*)&hbf[buf][l15][k * 32 + lg * 8];
                // slot s was loaded 8 iters ago; 28 = 7 iters x 4 loads younger.
                // vmem retires in order: compiler extras only over-wait, never under-wait.
                asm volatile("s_waitcnt vmcnt(28)");
                __builtin_amdgcn_sched_barrier(0);
                ai = __builtin_amdgcn_mfma_f32_16x16x32_bf16(av, bb[s][0], ai, 0, 0, 0);
                af = __builtin_amdgcn_mfma_f32_16x16x32_bf16(av, bb[s][1], af, 0, 0, 0);
                ag = __builtin_amdgcn_mfma_f32_16x16x32_bf16(av, bb[s][2], ag, 0, 0, 0);
                ao = __builtin_amdgcn_mfma_f32_16x16x32_bf16(av, bb[s][3], ao, 0, 0, 0);
                // refill slot for qi+PFD (wraps into next step; W is step-invariant)
                const short* p = wb_lane + (((qi + PFD) & 63) * 2048);
                asm volatile("global_load_dwordx4 %0, %1, off"             : "=v"(bb[s][0]) : "v"(p));
                asm volatile("global_load_dwordx4 %0, %1, off offset:1024" : "=v"(bb[s][1]) : "v"(p));
                asm volatile("global_load_dwordx4 %0, %1, off offset:2048" : "=v"(bb[s][2]) : "v"(p));
                asm volatile("global_load_dwordx4 %0, %1, off offset:3072" : "=v"(bb[s][3]) : "v"(p));
            }
            // gathers are older than the 32 outstanding W loads -> done at vmcnt(32)
            asm volatile("s_waitcnt vmcnt(32)");
            __builtin_amdgcn_sched_barrier(0);

#pragma unroll
            for (int q = 0; q < 4; ++q) {
                float gi = ai[q] + bf2f(wx[q][0]);
                float gf = af[q] + bf2f(wx[q][1]);
                float gg = ag[q] + bf2f(wx[q][2]);
                float go = ao[q] + bf2f(wx[q][3]);
                float cn = sigm(gf) * c[qd][q] + sigm(gi) * tanh_f(gg);
                c[qd][q] = cn;
                float hn = sigm(go) * tanh_f(cn);
                hbf[buf ^ 1][4 * lg + q][w * 64 + qd * 16 + l15] = f2bf(hn);
                ex[qd][q] = __expf(hn);   // h in (-1,1): no max-subtraction needed
            }
        }

        // per-row softmax-denominator + argmax partials (wave-level)
#pragma unroll
        for (int q = 0; q < 4; ++q) {
            float s = ex[0][q] + ex[1][q] + ex[2][q] + ex[3][q];
            float mv = ex[0][q]; int mi = w * 64 + l15;
#pragma unroll
            for (int qd = 1; qd < 4; ++qd) {
                int v = w * 64 + qd * 16 + l15;
                if (ex[qd][q] > mv) { mv = ex[qd][q]; mi = v; }
            }
#pragma unroll
            for (int m = 1; m < 16; m <<= 1) {
                s += __shfl_xor(s, m);
                float mv2 = __shfl_xor(mv, m);
                int   mi2 = __shfl_xor(mi, m);
                if (mv2 > mv || (mv2 == mv && mi2 < mi)) { mv = mv2; mi = mi2; }
            }
            if (l15 == 0) { int r = 4 * lg + q; wsum[w][r] = s; wmaxv[w][r] = mv; wmaxi[w][r] = mi; }
        }
        block_sync_lgkm();               // lgkm-only: W pipeline stays in flight
        if (tid < BT) {
            float s = 0.f;
#pragma unroll
            for (int ww = 0; ww < NW; ++ww) s += wsum[ww][tid];
            rinv[tid] = 1.0f / s;
            float mv = wmaxv[0][tid]; int mi = wmaxi[0][tid];
#pragma unroll
            for (int ww = 1; ww < NW; ++ww) {
                float mv2 = wmaxv[ww][tid]; int mi2 = wmaxi[ww][tid];
                if (mv2 > mv || (mv2 == mv && mi2 < mi)) { mv = mv2; mi = mi2; }
            }
            ridx[tid] = mi;
        }
        block_sync_lgkm();

        // write probas for step t (nontemporal: never re-read, keep L2 for Wb)
#pragma unroll
        for (int qd = 0; qd < 4; ++qd)
#pragma unroll
            for (int q = 0; q < 4; ++q) {
                int r = 4 * lg + q;
                __builtin_nontemporal_store(ex[qd][q] * rinv[r],
                    &out[((size_t)(row0 + r) * LSEQ + t) * VSZ + w * 64 + qd * 16 + l15]);
            }
        buf ^= 1;
    }
}

extern "C" void kernel_launch(void* const* d_in, const int* in_sizes, int n_in,
                              void* d_out, int out_size, void* d_ws, size_t ws_size,
                              hipStream_t stream) {
    const float* x    = (const float*)d_in[0];
    const float* W_ih = (const float*)d_in[1];
    const float* W_hh = (const float*)d_in[2];
    const float* b_ih = (const float*)d_in[3];
    const float* b_hh = (const float*)d_in[4];

    short* Wb  = (short*)d_ws;                 // 2 MB swizzled W_hh (bf16)
    short* Wxb = Wb + (size_t)2048 * 512;      // 2 MB one-hot gather table (bf16)

    prep_wb<<<256, NTHR, 0, stream>>>(W_hh, Wb);
    prep_wxb<<<dim3(32, 8), NTHR, 0, stream>>>(W_ih, b_ih, b_hh, Wxb);
    decoder_main<<<32, NTHR, 0, stream>>>(x, Wb, Wxb, (float*)d_out);
}